// Round 11
// baseline (1458.473 us; speedup 1.0000x reference)
//
#include <hip/hip_runtime.h>

// GCN 2-layer forward on MI355X.
// Pipeline: decode edge_index -> CSR build -> agg128(x) -> gemm+b1+relu
//           -> agg256(h) -> gemm+b2.
// R2: propagate-BEFORE-transform; bias+ReLU fused into GEMM epilogue.
// R3: agg128 half-wave-per-edge (16B/lane loads).
// R4: int64/int32 edge_index decode on device; OOB guards.
// R5: nontemporal loads for the single-use edge stream.
// R8: batch-16/32 MLP depth; packed int2 edge array. A/B result: agg256
//     FLAT (474->476us) -> NOT latency-bound; throughput wall in mem system.
// R9: DISCRIMINATOR — nontemporal STORES for agg outputs (zero read-reuse
//     until next kernel's streaming read). If L3-thrash hypothesis: removes
//     ~102MB L3 pollution during agg256 -> h stays L3-resident -> FETCH
//     1.6GB -> ~0.5GB, agg256 477 -> ~350us. If fabric-wall hypothesis:
//     flat -> next lever is bf16 h.
// R10: resubmit unchanged (infra timeout; the R9 A/B is still pending and
//     must land single-variable).

#define DF 256  // GEMM output width (both layers)

typedef float f4v __attribute__((ext_vector_type(4)));
__device__ inline void nt_store4(float* p, float4 v) {
  f4v t;
  t.x = v.x; t.y = v.y; t.z = v.z; t.w = v.w;
  __builtin_nontemporal_store(t, (f4v*)p);
}

// ---------------- utility ----------------
__global__ __launch_bounds__(256) void zero_i32(int* __restrict__ p, int n) {
  int i = blockIdx.x * blockDim.x + threadIdx.x;
  if (i < n) p[i] = 0;
}

// ---------------- edge_index dtype detection (int64 vs int32) ----------------
__global__ __launch_bounds__(256) void detect_kernel(const int* __restrict__ ei32,
                                                     int n_logical,
                                                     int* __restrict__ flag) {
  __shared__ int s_nonzero;
  if (threadIdx.x == 0) s_nonzero = 0;
  __syncthreads();
  const int n_half = n_logical >> 1;
  int step = n_half / 1024;
  if (step < 1) step = 1;
  for (int k = threadIdx.x; k < 1024; k += 256) {
    long idx = (long)k * step;
    if (idx < n_half && ei32[2 * idx + 1] != 0) atomicOr(&s_nonzero, 1);
  }
  __syncthreads();
  if (threadIdx.x == 0) flag[0] = s_nonzero ? 0 : 1;  // 1 => int64
}

// ---------------- decode to canonical int32 ----------------
__global__ __launch_bounds__(256) void convert_kernel(const int* __restrict__ ei32,
                                                      const int* __restrict__ flag,
                                                      int* __restrict__ conv, int n) {
  int i = blockIdx.x * blockDim.x + threadIdx.x;
  if (i < n) conv[i] = flag[0] ? ei32[2 * (size_t)i] : ei32[i];
}

// ---------------- degree histogram ----------------
__global__ __launch_bounds__(256) void count_kernel(const int* __restrict__ dst,
                                                    int* __restrict__ cnt, int E, int n) {
  int i = blockIdx.x * blockDim.x + threadIdx.x;
  if (i < E) {
    int d = dst[i];
    if ((unsigned)d < (unsigned)n) atomicAdd(&cnt[d], 1);
  }
}

// ---------------- single-block exclusive scan over n counts ----------------
__global__ __launch_bounds__(1024) void scan_kernel(const int* __restrict__ cnt,
                                                    int* __restrict__ row_ptr, int n) {
  __shared__ int wsum[16];
  __shared__ int s_base;
  const int tid = threadIdx.x;
  const int lane = tid & 63;
  const int wid = tid >> 6;
  if (tid == 0) s_base = 0;
  __syncthreads();
  for (int start = 0; start < n; start += 4096) {
    const int i0 = start + tid * 4;
    int v[4];
#pragma unroll
    for (int u = 0; u < 4; ++u) v[u] = (i0 + u < n) ? cnt[i0 + u] : 0;
    const int tsum = v[0] + v[1] + v[2] + v[3];
    int sc = tsum;  // inclusive wave scan of per-thread sums
#pragma unroll
    for (int off = 1; off < 64; off <<= 1) {
      int t = __shfl_up(sc, off);
      if (lane >= off) sc += t;
    }
    if (lane == 63) wsum[wid] = sc;
    __syncthreads();
    if (wid == 0) {
      int ws = (lane < 16) ? wsum[lane] : 0;
#pragma unroll
      for (int off = 1; off < 16; off <<= 1) {
        int t = __shfl_up(ws, off);
        if (lane >= off) ws += t;
      }
      if (lane < 16) wsum[lane] = ws;  // inclusive wave-sum scan
    }
    __syncthreads();
    int base = s_base + (wid > 0 ? wsum[wid - 1] : 0) + (sc - tsum);
#pragma unroll
    for (int u = 0; u < 4; ++u) {
      if (i0 + u < n) row_ptr[i0 + u] = base;
      base += v[u];
    }
    __syncthreads();
    if (tid == 1023) s_base += wsum[15];
    __syncthreads();
  }
  if (tid == 0) row_ptr[n] = s_base;
}

// ---------------- dinv = rsqrt(deg+1), cursor = row_ptr copy ----------------
__global__ __launch_bounds__(256) void dinv_cursor_kernel(const int* __restrict__ cnt,
                                                          const int* __restrict__ row_ptr,
                                                          float* __restrict__ dinv,
                                                          int* __restrict__ cursor, int n) {
  int i = blockIdx.x * blockDim.x + threadIdx.x;
  if (i < n) {
    dinv[i] = rsqrtf((float)(cnt[i] + 1));  // +1: self-loop; always >= 1
    cursor[i] = row_ptr[i];
  }
}

// ---------------- CSR fill: edge[] = {src, dinv[src]*dinv[dst]} packed ----------------
__global__ __launch_bounds__(256) void fill_kernel(const int* __restrict__ src,
                                                   const int* __restrict__ dst,
                                                   const float* __restrict__ dinv,
                                                   int* __restrict__ cursor,
                                                   int2* __restrict__ edge, int E, int n) {
  int i = blockIdx.x * blockDim.x + threadIdx.x;
  if (i < E) {
    int s = src[i], d = dst[i];
    if ((unsigned)s < (unsigned)n && (unsigned)d < (unsigned)n) {
      int pos = atomicAdd(&cursor[d], 1);
      edge[pos] = make_int2(s, __float_as_int(dinv[s] * dinv[d]));  // one 8B scatter
    }
  }
}

// ---------------- fp32 GEMM: out[M,256] = X[M,K] @ W[K,256] + b (opt ReLU) ----------------
template <int K, bool RELU>
__global__ __launch_bounds__(256) void gemm_kernel(const float* __restrict__ X,
                                                   const float* __restrict__ W,
                                                   const float* __restrict__ bias,
                                                   float* __restrict__ out, int M) {
  __shared__ float xs[32][K];  // 16KB (K=128) or 32KB (K=256)
  const int t = threadIdx.x;
  const int row0 = blockIdx.x * 32;

  for (int i = t; i < 8 * K; i += 256) {  // 32*K/4 float4s
    int r = i / (K / 4);
    int kk = (i % (K / 4)) * 4;
    int gr = row0 + r;
    float4 v = make_float4(0.f, 0.f, 0.f, 0.f);
    if (gr < M) v = *(const float4*)&X[(size_t)gr * K + kk];
    *(float4*)&xs[r][kk] = v;
  }
  __syncthreads();

  const int c = (t & 63) * 4;   // column group (float4 along N)
  const int r0 = (t >> 6) * 8;  // 8 rows per thread
  float4 acc[8];
#pragma unroll
  for (int i = 0; i < 8; ++i) acc[i] = make_float4(0.f, 0.f, 0.f, 0.f);

  for (int k = 0; k < K; k += 4) {
    float4 wv[4];
#pragma unroll
    for (int j = 0; j < 4; ++j) wv[j] = *(const float4*)&W[(size_t)(k + j) * DF + c];
#pragma unroll
    for (int i = 0; i < 8; ++i) {
      float4 xv = *(const float4*)&xs[r0 + i][k];  // wave-broadcast LDS read
      acc[i].x = fmaf(xv.x, wv[0].x, acc[i].x);
      acc[i].y = fmaf(xv.x, wv[0].y, acc[i].y);
      acc[i].z = fmaf(xv.x, wv[0].z, acc[i].z);
      acc[i].w = fmaf(xv.x, wv[0].w, acc[i].w);
      acc[i].x = fmaf(xv.y, wv[1].x, acc[i].x);
      acc[i].y = fmaf(xv.y, wv[1].y, acc[i].y);
      acc[i].z = fmaf(xv.y, wv[1].z, acc[i].z);
      acc[i].w = fmaf(xv.y, wv[1].w, acc[i].w);
      acc[i].x = fmaf(xv.z, wv[2].x, acc[i].x);
      acc[i].y = fmaf(xv.z, wv[2].y, acc[i].y);
      acc[i].z = fmaf(xv.z, wv[2].z, acc[i].z);
      acc[i].w = fmaf(xv.z, wv[2].w, acc[i].w);
      acc[i].x = fmaf(xv.w, wv[3].x, acc[i].x);
      acc[i].y = fmaf(xv.w, wv[3].y, acc[i].y);
      acc[i].z = fmaf(xv.w, wv[3].z, acc[i].z);
      acc[i].w = fmaf(xv.w, wv[3].w, acc[i].w);
    }
  }

  const float4 bv = *(const float4*)&bias[c];
#pragma unroll
  for (int i = 0; i < 8; ++i) {
    int gr = row0 + r0 + i;
    if (gr < M) {
      float4 r;
      r.x = acc[i].x + bv.x;
      r.y = acc[i].y + bv.y;
      r.z = acc[i].z + bv.z;
      r.w = acc[i].w + bv.w;
      if (RELU) {
        r.x = fmaxf(r.x, 0.f);
        r.y = fmaxf(r.y, 0.f);
        r.z = fmaxf(r.z, 0.f);
        r.w = fmaxf(r.w, 0.f);
      }
      *(float4*)&out[(size_t)gr * DF + c] = r;  // NORMAL store: agg256 gathers this
    }
  }
}

// ---------------- CSR aggregation, D=256: one wave per node, batch-16 ----------------
__global__ __launch_bounds__(256) void agg256_kernel(const float* __restrict__ h,
                                                     const int* __restrict__ row_ptr,
                                                     const int2* __restrict__ edge,
                                                     const float* __restrict__ dinv,
                                                     float* __restrict__ out, int n) {
  int wid = (blockIdx.x * blockDim.x + threadIdx.x) >> 6;  // node = wave id
  int lane = threadIdx.x & 63;
  if (wid >= n) return;
  int start = row_ptr[wid];
  int end = row_ptr[wid + 1];
  const int foff = lane * 4;

  float4 acc = make_float4(0.f, 0.f, 0.f, 0.f);
  for (int base = start; base < end; base += 64) {
    int e = base + lane;
    int ce = 0;
    float we = 0.f;
    if (e < end) {
      long long ev = __builtin_nontemporal_load((const long long*)edge + e);
      ce = (int)(ev & 0xffffffffLL);
      we = __int_as_float((int)(ev >> 32));
    }
    int m = end - base;
    if (m > 64) m = 64;
    int j = 0;
    for (; j + 16 <= m; j += 16) {  // 16 outstanding 1KB gathers (R8)
      float4 hv[16];
      float ww[16];
#pragma unroll
      for (int u = 0; u < 16; ++u) {
        int s = __shfl(ce, j + u);
        ww[u] = __shfl(we, j + u);
        hv[u] = *(const float4*)&h[(size_t)s * 256 + foff];
      }
#pragma unroll
      for (int u = 0; u < 16; ++u) {
        acc.x = fmaf(hv[u].x, ww[u], acc.x);
        acc.y = fmaf(hv[u].y, ww[u], acc.y);
        acc.z = fmaf(hv[u].z, ww[u], acc.z);
        acc.w = fmaf(hv[u].w, ww[u], acc.w);
      }
    }
    for (; j + 8 <= m; j += 8) {
      float4 hv[8];
      float ww[8];
#pragma unroll
      for (int u = 0; u < 8; ++u) {
        int s = __shfl(ce, j + u);
        ww[u] = __shfl(we, j + u);
        hv[u] = *(const float4*)&h[(size_t)s * 256 + foff];
      }
#pragma unroll
      for (int u = 0; u < 8; ++u) {
        acc.x = fmaf(hv[u].x, ww[u], acc.x);
        acc.y = fmaf(hv[u].y, ww[u], acc.y);
        acc.z = fmaf(hv[u].z, ww[u], acc.z);
        acc.w = fmaf(hv[u].w, ww[u], acc.w);
      }
    }
    for (; j < m; ++j) {
      int s = __shfl(ce, j);
      float ww = __shfl(we, j);
      float4 hv = *(const float4*)&h[(size_t)s * 256 + foff];
      acc.x = fmaf(hv.x, ww, acc.x);
      acc.y = fmaf(hv.y, ww, acc.y);
      acc.z = fmaf(hv.z, ww, acc.z);
      acc.w = fmaf(hv.w, ww, acc.w);
    }
  }
  // self-loop
  float di = dinv[wid];
  float sw = di * di;
  float4 own = *(const float4*)&h[(size_t)wid * 256 + foff];
  acc.x = fmaf(own.x, sw, acc.x);
  acc.y = fmaf(own.y, sw, acc.y);
  acc.z = fmaf(own.z, sw, acc.z);
  acc.w = fmaf(own.w, sw, acc.w);
  nt_store4(&out[(size_t)wid * 256 + foff], acc);  // R9: bypass cache alloc
}

// ---------------- CSR aggregation, D=128: half-wave per edge, batch-32 ----------------
__global__ __launch_bounds__(256) void agg128_kernel(const float* __restrict__ h,
                                                     const int* __restrict__ row_ptr,
                                                     const int2* __restrict__ edge,
                                                     const float* __restrict__ dinv,
                                                     float* __restrict__ out, int n) {
  int wid = (blockIdx.x * blockDim.x + threadIdx.x) >> 6;  // node = wave id
  int lane = threadIdx.x & 63;
  if (wid >= n) return;
  int start = row_ptr[wid];
  int end = row_ptr[wid + 1];
  const int half = lane >> 5;         // 0 or 1
  const int foff = (lane & 31) * 4;   // feature offset within the 128-row

  float4 acc = make_float4(0.f, 0.f, 0.f, 0.f);
  for (int base = start; base < end; base += 64) {
    int e = base + lane;
    int ce = 0;
    float we = 0.f;
    if (e < end) {
      long long ev = __builtin_nontemporal_load((const long long*)edge + e);
      ce = (int)(ev & 0xffffffffLL);
      we = __int_as_float((int)(ev >> 32));
    }
    int m = end - base;
    if (m > 64) m = 64;
    int j = 0;
    for (; j + 32 <= m; j += 32) {  // 16 iters x 2 edges -> 16 outstanding (R8)
      float4 hv[16];
      float ww[16];
#pragma unroll
      for (int u = 0; u < 16; ++u) {
        int idx = j + 2 * u + half;
        int s = __shfl(ce, idx);
        ww[u] = __shfl(we, idx);
        hv[u] = *(const float4*)&h[(size_t)s * 128 + foff];
      }
#pragma unroll
      for (int u = 0; u < 16; ++u) {
        acc.x = fmaf(hv[u].x, ww[u], acc.x);
        acc.y = fmaf(hv[u].y, ww[u], acc.y);
        acc.z = fmaf(hv[u].z, ww[u], acc.z);
        acc.w = fmaf(hv[u].w, ww[u], acc.w);
      }
    }
    for (; j + 16 <= m; j += 16) {  // 8 iters x 2 edges
      float4 hv[8];
      float ww[8];
#pragma unroll
      for (int u = 0; u < 8; ++u) {
        int idx = j + 2 * u + half;
        int s = __shfl(ce, idx);
        ww[u] = __shfl(we, idx);
        hv[u] = *(const float4*)&h[(size_t)s * 128 + foff];
      }
#pragma unroll
      for (int u = 0; u < 8; ++u) {
        acc.x = fmaf(hv[u].x, ww[u], acc.x);
        acc.y = fmaf(hv[u].y, ww[u], acc.y);
        acc.z = fmaf(hv[u].z, ww[u], acc.z);
        acc.w = fmaf(hv[u].w, ww[u], acc.w);
      }
    }
    for (; j + 2 <= m; j += 2) {  // leftover pairs
      int idx = j + half;
      int s = __shfl(ce, idx);
      float ww = __shfl(we, idx);
      float4 hv = *(const float4*)&h[(size_t)s * 128 + foff];
      acc.x = fmaf(hv.x, ww, acc.x);
      acc.y = fmaf(hv.y, ww, acc.y);
      acc.z = fmaf(hv.z, ww, acc.z);
      acc.w = fmaf(hv.w, ww, acc.w);
    }
    if (j < m) {  // single leftover edge: half 0 only
      int s = __shfl(ce, j);
      float ww = __shfl(we, j);
      if (half == 0) {
        float4 hv = *(const float4*)&h[(size_t)s * 128 + foff];
        acc.x = fmaf(hv.x, ww, acc.x);
        acc.y = fmaf(hv.y, ww, acc.y);
        acc.z = fmaf(hv.z, ww, acc.z);
        acc.w = fmaf(hv.w, ww, acc.w);
      }
    }
  }
  // combine the two half-wave partial sums
  acc.x += __shfl_xor(acc.x, 32);
  acc.y += __shfl_xor(acc.y, 32);
  acc.z += __shfl_xor(acc.z, 32);
  acc.w += __shfl_xor(acc.w, 32);
  if (half == 0) {
    float di = dinv[wid];
    float sw = di * di;
    float4 own = *(const float4*)&h[(size_t)wid * 128 + foff];
    acc.x = fmaf(own.x, sw, acc.x);
    acc.y = fmaf(own.y, sw, acc.y);
    acc.z = fmaf(own.z, sw, acc.z);
    acc.w = fmaf(own.w, sw, acc.w);
    nt_store4(&out[(size_t)wid * 128 + foff], acc);  // R9: bypass cache alloc
  }
}

// ---------------- launch ----------------
extern "C" void kernel_launch(void* const* d_in, const int* in_sizes, int n_in,
                              void* d_out, int out_size, void* d_ws, size_t ws_size,
                              hipStream_t stream) {
  const float* x = (const float*)d_in[0];
  const int* ei = (const int*)d_in[1];  // raw words; dtype resolved on-device (R4)
  const float* W1 = (const float*)d_in[2];
  const float* b1 = (const float*)d_in[3];
  const float* W2 = (const float*)d_in[4];
  const float* b2 = (const float*)d_in[5];
  float* out = (float*)d_out;

  const int N = in_sizes[0] / 128;   // 100000
  const int NE2 = in_sizes[1];       // 2*E logical int elements
  const int E = NE2 / 2;             // 3200000

  // workspace carve (256B aligned); total ~129.3MB
  char* p = (char*)d_ws;
  auto carve = [&](size_t bytes) {
    void* q = (void*)p;
    p += (bytes + 255) & ~(size_t)255;
    return q;
  };
  int* flag = (int*)carve(4);
  int* cnt = (int*)carve((size_t)N * 4);
  int* row_ptr = (int*)carve((size_t)(N + 1) * 4);
  int* cursor = (int*)carve((size_t)N * 4);
  float* dinv = (float*)carve((size_t)N * 4);
  int2* edge = (int2*)carve((size_t)E * 8);  // packed (col, w)
  float* buf = (float*)carve((size_t)N * DF * 4);  // 102.4MB; serves ax & ah
  // decoded edge_index aliases buf's head (dead until agg128 runs)
  int* conv = (int*)buf;
  const int* src = conv;
  const int* dst = conv + E;

  // ---- decode edge_index (int64 vs int32, device-side) ----
  detect_kernel<<<1, 256, 0, stream>>>(ei, NE2, flag);
  convert_kernel<<<(NE2 + 255) / 256, 256, 0, stream>>>(ei, flag, conv, NE2);

  // ---- CSR build (shared by both layers) ----
  zero_i32<<<(N + 255) / 256, 256, 0, stream>>>(cnt, N);
  count_kernel<<<(E + 255) / 256, 256, 0, stream>>>(dst, cnt, E, N);
  scan_kernel<<<1, 1024, 0, stream>>>(cnt, row_ptr, N);
  dinv_cursor_kernel<<<(N + 255) / 256, 256, 0, stream>>>(cnt, row_ptr, dinv, cursor, N);
  fill_kernel<<<(E + 255) / 256, 256, 0, stream>>>(src, dst, dinv, cursor, edge, E, N);

  const int agg_blocks = (N * 64 + 255) / 256;  // one wave per node

  // ---- layer 1: ax = A_hat x ; h = relu(ax @ W1 + b1) -> d_out ----
  agg128_kernel<<<agg_blocks, 256, 0, stream>>>(x, row_ptr, edge, dinv, buf, N);
  gemm_kernel<128, true><<<(N + 31) / 32, 256, 0, stream>>>(buf, W1, b1, out, N);

  // ---- layer 2: ah = A_hat h ; out = ah @ W2 + b2 -> d_out ----
  agg256_kernel<<<agg_blocks, 256, 0, stream>>>(out, row_ptr, edge, dinv, buf, N);
  gemm_kernel<256, false><<<(N + 31) / 32, 256, 0, stream>>>(buf, W2, b2, out, N);
}

// Round 12
// 1183.730 us; speedup vs baseline: 1.2321x; 1.2321x over previous
//
#include <hip/hip_runtime.h>

// GCN 2-layer forward on MI355X.
// Pipeline: decode edge_index -> CSR build -> agg128(x) -> gemm+b1+relu(bf16 out)
//           -> agg256(bf16 h) -> gemm+b2.
// R2: propagate-BEFORE-transform; bias+ReLU fused into GEMM epilogue.
// R3: agg128 half-wave-per-edge (16B/lane loads).
// R4: int64/int32 edge_index decode on device; OOB guards.
// R5: nontemporal loads for the single-use edge stream.
// R8: batch-16/32 MLP depth; packed edges. A/B: FLAT -> not latency-bound.
// R9: nt agg stores. A/B: FLAT, FETCH unchanged -> fabric/EA wall at
//     ~3.4TB/s; L2 absorbs 50% of 3.28GB logical; only lever left = bytes.
// R11: bf16 gather source for agg256 (the 473us dominant dispatch): gemm1
//     epilogue emits bf16 h (51MB, lives in d_out between gemms); agg256
//     gathers ushort4 (8B/lane), converts in-register, accumulates fp32.
//     Predict: FETCH 1.6->~0.6-0.8GB, agg256 473->~250-300us, absmax ~4e-3.

#define DF 256  // GEMM output width (both layers)

typedef float f4v __attribute__((ext_vector_type(4)));
__device__ inline void nt_store4(float* p, float4 v) {
  f4v t;
  t.x = v.x; t.y = v.y; t.z = v.z; t.w = v.w;
  __builtin_nontemporal_store(t, (f4v*)p);
}
__device__ inline unsigned short f2bf(float f) {  // round-to-nearest-even
  unsigned u = __float_as_uint(f);
  return (unsigned short)((u + 0x7FFFu + ((u >> 16) & 1u)) >> 16);
}
__device__ inline float bf2f(unsigned short h) {
  return __uint_as_float(((unsigned)h) << 16);
}

// ---------------- utility ----------------
__global__ __launch_bounds__(256) void zero_i32(int* __restrict__ p, int n) {
  int i = blockIdx.x * blockDim.x + threadIdx.x;
  if (i < n) p[i] = 0;
}

// ---------------- edge_index dtype detection (int64 vs int32) ----------------
__global__ __launch_bounds__(256) void detect_kernel(const int* __restrict__ ei32,
                                                     int n_logical,
                                                     int* __restrict__ flag) {
  __shared__ int s_nonzero;
  if (threadIdx.x == 0) s_nonzero = 0;
  __syncthreads();
  const int n_half = n_logical >> 1;
  int step = n_half / 1024;
  if (step < 1) step = 1;
  for (int k = threadIdx.x; k < 1024; k += 256) {
    long idx = (long)k * step;
    if (idx < n_half && ei32[2 * idx + 1] != 0) atomicOr(&s_nonzero, 1);
  }
  __syncthreads();
  if (threadIdx.x == 0) flag[0] = s_nonzero ? 0 : 1;  // 1 => int64
}

// ---------------- decode to canonical int32 ----------------
__global__ __launch_bounds__(256) void convert_kernel(const int* __restrict__ ei32,
                                                      const int* __restrict__ flag,
                                                      int* __restrict__ conv, int n) {
  int i = blockIdx.x * blockDim.x + threadIdx.x;
  if (i < n) conv[i] = flag[0] ? ei32[2 * (size_t)i] : ei32[i];
}

// ---------------- degree histogram ----------------
__global__ __launch_bounds__(256) void count_kernel(const int* __restrict__ dst,
                                                    int* __restrict__ cnt, int E, int n) {
  int i = blockIdx.x * blockDim.x + threadIdx.x;
  if (i < E) {
    int d = dst[i];
    if ((unsigned)d < (unsigned)n) atomicAdd(&cnt[d], 1);
  }
}

// ---------------- single-block exclusive scan over n counts ----------------
__global__ __launch_bounds__(1024) void scan_kernel(const int* __restrict__ cnt,
                                                    int* __restrict__ row_ptr, int n) {
  __shared__ int wsum[16];
  __shared__ int s_base;
  const int tid = threadIdx.x;
  const int lane = tid & 63;
  const int wid = tid >> 6;
  if (tid == 0) s_base = 0;
  __syncthreads();
  for (int start = 0; start < n; start += 4096) {
    const int i0 = start + tid * 4;
    int v[4];
#pragma unroll
    for (int u = 0; u < 4; ++u) v[u] = (i0 + u < n) ? cnt[i0 + u] : 0;
    const int tsum = v[0] + v[1] + v[2] + v[3];
    int sc = tsum;  // inclusive wave scan of per-thread sums
#pragma unroll
    for (int off = 1; off < 64; off <<= 1) {
      int t = __shfl_up(sc, off);
      if (lane >= off) sc += t;
    }
    if (lane == 63) wsum[wid] = sc;
    __syncthreads();
    if (wid == 0) {
      int ws = (lane < 16) ? wsum[lane] : 0;
#pragma unroll
      for (int off = 1; off < 16; off <<= 1) {
        int t = __shfl_up(ws, off);
        if (lane >= off) ws += t;
      }
      if (lane < 16) wsum[lane] = ws;  // inclusive wave-sum scan
    }
    __syncthreads();
    int base = s_base + (wid > 0 ? wsum[wid - 1] : 0) + (sc - tsum);
#pragma unroll
    for (int u = 0; u < 4; ++u) {
      if (i0 + u < n) row_ptr[i0 + u] = base;
      base += v[u];
    }
    __syncthreads();
    if (tid == 1023) s_base += wsum[15];
    __syncthreads();
  }
  if (tid == 0) row_ptr[n] = s_base;
}

// ---------------- dinv = rsqrt(deg+1), cursor = row_ptr copy ----------------
__global__ __launch_bounds__(256) void dinv_cursor_kernel(const int* __restrict__ cnt,
                                                          const int* __restrict__ row_ptr,
                                                          float* __restrict__ dinv,
                                                          int* __restrict__ cursor, int n) {
  int i = blockIdx.x * blockDim.x + threadIdx.x;
  if (i < n) {
    dinv[i] = rsqrtf((float)(cnt[i] + 1));  // +1: self-loop; always >= 1
    cursor[i] = row_ptr[i];
  }
}

// ---------------- CSR fill: edge[] = {src, dinv[src]*dinv[dst]} packed ----------------
__global__ __launch_bounds__(256) void fill_kernel(const int* __restrict__ src,
                                                   const int* __restrict__ dst,
                                                   const float* __restrict__ dinv,
                                                   int* __restrict__ cursor,
                                                   int2* __restrict__ edge, int E, int n) {
  int i = blockIdx.x * blockDim.x + threadIdx.x;
  if (i < E) {
    int s = src[i], d = dst[i];
    if ((unsigned)s < (unsigned)n && (unsigned)d < (unsigned)n) {
      int pos = atomicAdd(&cursor[d], 1);
      edge[pos] = make_int2(s, __float_as_int(dinv[s] * dinv[d]));  // one 8B scatter
    }
  }
}

// ---------------- fp32 GEMM: out = X[M,K] @ W[K,256] + b (opt ReLU, opt bf16 out) ----------------
template <int K, bool RELU, bool OBF16>
__global__ __launch_bounds__(256) void gemm_kernel(const float* __restrict__ X,
                                                   const float* __restrict__ W,
                                                   const float* __restrict__ bias,
                                                   void* __restrict__ outv, int M) {
  __shared__ float xs[32][K];  // 16KB (K=128) or 32KB (K=256)
  const int t = threadIdx.x;
  const int row0 = blockIdx.x * 32;

  for (int i = t; i < 8 * K; i += 256) {  // 32*K/4 float4s
    int r = i / (K / 4);
    int kk = (i % (K / 4)) * 4;
    int gr = row0 + r;
    float4 v = make_float4(0.f, 0.f, 0.f, 0.f);
    if (gr < M) v = *(const float4*)&X[(size_t)gr * K + kk];
    *(float4*)&xs[r][kk] = v;
  }
  __syncthreads();

  const int c = (t & 63) * 4;   // column group (float4 along N)
  const int r0 = (t >> 6) * 8;  // 8 rows per thread
  float4 acc[8];
#pragma unroll
  for (int i = 0; i < 8; ++i) acc[i] = make_float4(0.f, 0.f, 0.f, 0.f);

  for (int k = 0; k < K; k += 4) {
    float4 wv[4];
#pragma unroll
    for (int j = 0; j < 4; ++j) wv[j] = *(const float4*)&W[(size_t)(k + j) * DF + c];
#pragma unroll
    for (int i = 0; i < 8; ++i) {
      float4 xv = *(const float4*)&xs[r0 + i][k];  // wave-broadcast LDS read
      acc[i].x = fmaf(xv.x, wv[0].x, acc[i].x);
      acc[i].y = fmaf(xv.x, wv[0].y, acc[i].y);
      acc[i].z = fmaf(xv.x, wv[0].z, acc[i].z);
      acc[i].w = fmaf(xv.x, wv[0].w, acc[i].w);
      acc[i].x = fmaf(xv.y, wv[1].x, acc[i].x);
      acc[i].y = fmaf(xv.y, wv[1].y, acc[i].y);
      acc[i].z = fmaf(xv.y, wv[1].z, acc[i].z);
      acc[i].w = fmaf(xv.y, wv[1].w, acc[i].w);
      acc[i].x = fmaf(xv.z, wv[2].x, acc[i].x);
      acc[i].y = fmaf(xv.z, wv[2].y, acc[i].y);
      acc[i].z = fmaf(xv.z, wv[2].z, acc[i].z);
      acc[i].w = fmaf(xv.z, wv[2].w, acc[i].w);
      acc[i].x = fmaf(xv.w, wv[3].x, acc[i].x);
      acc[i].y = fmaf(xv.w, wv[3].y, acc[i].y);
      acc[i].z = fmaf(xv.w, wv[3].z, acc[i].z);
      acc[i].w = fmaf(xv.w, wv[3].w, acc[i].w);
    }
  }

  const float4 bv = *(const float4*)&bias[c];
#pragma unroll
  for (int i = 0; i < 8; ++i) {
    int gr = row0 + r0 + i;
    if (gr < M) {
      float4 r;
      r.x = acc[i].x + bv.x;
      r.y = acc[i].y + bv.y;
      r.z = acc[i].z + bv.z;
      r.w = acc[i].w + bv.w;
      if (RELU) {
        r.x = fmaxf(r.x, 0.f);
        r.y = fmaxf(r.y, 0.f);
        r.z = fmaxf(r.z, 0.f);
        r.w = fmaxf(r.w, 0.f);
      }
      if (OBF16) {
        ushort4 hq;
        hq.x = f2bf(r.x);
        hq.y = f2bf(r.y);
        hq.z = f2bf(r.z);
        hq.w = f2bf(r.w);
        *(ushort4*)&((unsigned short*)outv)[(size_t)gr * DF + c] = hq;
      } else {
        *(float4*)&((float*)outv)[(size_t)gr * DF + c] = r;
      }
    }
  }
}

// ---------------- CSR aggregation, D=256, bf16 source: one wave/node, batch-16 ----------------
// Lane l owns features [4l,4l+4): gathers ushort4 (8B); 64 lanes = 512B row.
__global__ __launch_bounds__(256) void agg256_kernel(const unsigned short* __restrict__ hb,
                                                     const int* __restrict__ row_ptr,
                                                     const int2* __restrict__ edge,
                                                     const float* __restrict__ dinv,
                                                     float* __restrict__ out, int n) {
  int wid = (blockIdx.x * blockDim.x + threadIdx.x) >> 6;  // node = wave id
  int lane = threadIdx.x & 63;
  if (wid >= n) return;
  int start = row_ptr[wid];
  int end = row_ptr[wid + 1];
  const int foff = lane * 4;

  float4 acc = make_float4(0.f, 0.f, 0.f, 0.f);
  for (int base = start; base < end; base += 64) {
    int e = base + lane;
    int ce = 0;
    float we = 0.f;
    if (e < end) {
      long long ev = __builtin_nontemporal_load((const long long*)edge + e);
      ce = (int)(ev & 0xffffffffLL);
      we = __int_as_float((int)(ev >> 32));
    }
    int m = end - base;
    if (m > 64) m = 64;
    int j = 0;
    for (; j + 16 <= m; j += 16) {  // 16 outstanding 512B gathers
      ushort4 hq[16];
      float ww[16];
#pragma unroll
      for (int u = 0; u < 16; ++u) {
        int s = __shfl(ce, j + u);
        ww[u] = __shfl(we, j + u);
        hq[u] = *(const ushort4*)&hb[(size_t)s * 256 + foff];
      }
#pragma unroll
      for (int u = 0; u < 16; ++u) {
        acc.x = fmaf(bf2f(hq[u].x), ww[u], acc.x);
        acc.y = fmaf(bf2f(hq[u].y), ww[u], acc.y);
        acc.z = fmaf(bf2f(hq[u].z), ww[u], acc.z);
        acc.w = fmaf(bf2f(hq[u].w), ww[u], acc.w);
      }
    }
    for (; j + 8 <= m; j += 8) {
      ushort4 hq[8];
      float ww[8];
#pragma unroll
      for (int u = 0; u < 8; ++u) {
        int s = __shfl(ce, j + u);
        ww[u] = __shfl(we, j + u);
        hq[u] = *(const ushort4*)&hb[(size_t)s * 256 + foff];
      }
#pragma unroll
      for (int u = 0; u < 8; ++u) {
        acc.x = fmaf(bf2f(hq[u].x), ww[u], acc.x);
        acc.y = fmaf(bf2f(hq[u].y), ww[u], acc.y);
        acc.z = fmaf(bf2f(hq[u].z), ww[u], acc.z);
        acc.w = fmaf(bf2f(hq[u].w), ww[u], acc.w);
      }
    }
    for (; j < m; ++j) {
      int s = __shfl(ce, j);
      float ww = __shfl(we, j);
      ushort4 hq = *(const ushort4*)&hb[(size_t)s * 256 + foff];
      acc.x = fmaf(bf2f(hq.x), ww, acc.x);
      acc.y = fmaf(bf2f(hq.y), ww, acc.y);
      acc.z = fmaf(bf2f(hq.z), ww, acc.z);
      acc.w = fmaf(bf2f(hq.w), ww, acc.w);
    }
  }
  // self-loop
  float di = dinv[wid];
  float sw = di * di;
  ushort4 hq = *(const ushort4*)&hb[(size_t)wid * 256 + foff];
  acc.x = fmaf(bf2f(hq.x), sw, acc.x);
  acc.y = fmaf(bf2f(hq.y), sw, acc.y);
  acc.z = fmaf(bf2f(hq.z), sw, acc.z);
  acc.w = fmaf(bf2f(hq.w), sw, acc.w);
  nt_store4(&out[(size_t)wid * 256 + foff], acc);
}

// ---------------- CSR aggregation, D=128 fp32: half-wave per edge, batch-32 ----------------
__global__ __launch_bounds__(256) void agg128_kernel(const float* __restrict__ h,
                                                     const int* __restrict__ row_ptr,
                                                     const int2* __restrict__ edge,
                                                     const float* __restrict__ dinv,
                                                     float* __restrict__ out, int n) {
  int wid = (blockIdx.x * blockDim.x + threadIdx.x) >> 6;  // node = wave id
  int lane = threadIdx.x & 63;
  if (wid >= n) return;
  int start = row_ptr[wid];
  int end = row_ptr[wid + 1];
  const int half = lane >> 5;         // 0 or 1
  const int foff = (lane & 31) * 4;   // feature offset within the 128-row

  float4 acc = make_float4(0.f, 0.f, 0.f, 0.f);
  for (int base = start; base < end; base += 64) {
    int e = base + lane;
    int ce = 0;
    float we = 0.f;
    if (e < end) {
      long long ev = __builtin_nontemporal_load((const long long*)edge + e);
      ce = (int)(ev & 0xffffffffLL);
      we = __int_as_float((int)(ev >> 32));
    }
    int m = end - base;
    if (m > 64) m = 64;
    int j = 0;
    for (; j + 32 <= m; j += 32) {  // 16 iters x 2 edges -> 16 outstanding
      float4 hv[16];
      float ww[16];
#pragma unroll
      for (int u = 0; u < 16; ++u) {
        int idx = j + 2 * u + half;
        int s = __shfl(ce, idx);
        ww[u] = __shfl(we, idx);
        hv[u] = *(const float4*)&h[(size_t)s * 128 + foff];
      }
#pragma unroll
      for (int u = 0; u < 16; ++u) {
        acc.x = fmaf(hv[u].x, ww[u], acc.x);
        acc.y = fmaf(hv[u].y, ww[u], acc.y);
        acc.z = fmaf(hv[u].z, ww[u], acc.z);
        acc.w = fmaf(hv[u].w, ww[u], acc.w);
      }
    }
    for (; j + 16 <= m; j += 16) {  // 8 iters x 2 edges
      float4 hv[8];
      float ww[8];
#pragma unroll
      for (int u = 0; u < 8; ++u) {
        int idx = j + 2 * u + half;
        int s = __shfl(ce, idx);
        ww[u] = __shfl(we, idx);
        hv[u] = *(const float4*)&h[(size_t)s * 128 + foff];
      }
#pragma unroll
      for (int u = 0; u < 8; ++u) {
        acc.x = fmaf(hv[u].x, ww[u], acc.x);
        acc.y = fmaf(hv[u].y, ww[u], acc.y);
        acc.z = fmaf(hv[u].z, ww[u], acc.z);
        acc.w = fmaf(hv[u].w, ww[u], acc.w);
      }
    }
    for (; j + 2 <= m; j += 2) {  // leftover pairs
      int idx = j + half;
      int s = __shfl(ce, idx);
      float ww = __shfl(we, idx);
      float4 hv = *(const float4*)&h[(size_t)s * 128 + foff];
      acc.x = fmaf(hv.x, ww, acc.x);
      acc.y = fmaf(hv.y, ww, acc.y);
      acc.z = fmaf(hv.z, ww, acc.z);
      acc.w = fmaf(hv.w, ww, acc.w);
    }
    if (j < m) {  // single leftover edge: half 0 only
      int s = __shfl(ce, j);
      float ww = __shfl(we, j);
      if (half == 0) {
        float4 hv = *(const float4*)&h[(size_t)s * 128 + foff];
        acc.x = fmaf(hv.x, ww, acc.x);
        acc.y = fmaf(hv.y, ww, acc.y);
        acc.z = fmaf(hv.z, ww, acc.z);
        acc.w = fmaf(hv.w, ww, acc.w);
      }
    }
  }
  // combine the two half-wave partial sums
  acc.x += __shfl_xor(acc.x, 32);
  acc.y += __shfl_xor(acc.y, 32);
  acc.z += __shfl_xor(acc.z, 32);
  acc.w += __shfl_xor(acc.w, 32);
  if (half == 0) {
    float di = dinv[wid];
    float sw = di * di;
    float4 own = *(const float4*)&h[(size_t)wid * 128 + foff];
    acc.x = fmaf(own.x, sw, acc.x);
    acc.y = fmaf(own.y, sw, acc.y);
    acc.z = fmaf(own.z, sw, acc.z);
    acc.w = fmaf(own.w, sw, acc.w);
    nt_store4(&out[(size_t)wid * 128 + foff], acc);
  }
}

// ---------------- launch ----------------
extern "C" void kernel_launch(void* const* d_in, const int* in_sizes, int n_in,
                              void* d_out, int out_size, void* d_ws, size_t ws_size,
                              hipStream_t stream) {
  const float* x = (const float*)d_in[0];
  const int* ei = (const int*)d_in[1];  // raw words; dtype resolved on-device (R4)
  const float* W1 = (const float*)d_in[2];
  const float* b1 = (const float*)d_in[3];
  const float* W2 = (const float*)d_in[4];
  const float* b2 = (const float*)d_in[5];

  const int N = in_sizes[0] / 128;   // 100000
  const int NE2 = in_sizes[1];       // 2*E logical int elements
  const int E = NE2 / 2;             // 3200000

  // workspace carve (256B aligned); total ~129.3MB
  char* p = (char*)d_ws;
  auto carve = [&](size_t bytes) {
    void* q = (void*)p;
    p += (bytes + 255) & ~(size_t)255;
    return q;
  };
  int* flag = (int*)carve(4);
  int* cnt = (int*)carve((size_t)N * 4);
  int* row_ptr = (int*)carve((size_t)(N + 1) * 4);
  int* cursor = (int*)carve((size_t)N * 4);
  float* dinv = (float*)carve((size_t)N * 4);
  int2* edge = (int2*)carve((size_t)E * 8);  // packed (col, w)
  float* buf = (float*)carve((size_t)N * DF * 4);  // 102.4MB; serves ax & ah
  // decoded edge_index aliases buf's head (dead until agg128 runs)
  int* conv = (int*)buf;
  const int* src = conv;
  const int* dst = conv + E;
  // bf16 h lives in d_out between gemm1 and gemm2 (51MB of the 102MB buffer)
  unsigned short* hb = (unsigned short*)d_out;

  // ---- decode edge_index (int64 vs int32, device-side) ----
  detect_kernel<<<1, 256, 0, stream>>>(ei, NE2, flag);
  convert_kernel<<<(NE2 + 255) / 256, 256, 0, stream>>>(ei, flag, conv, NE2);

  // ---- CSR build (shared by both layers) ----
  zero_i32<<<(N + 255) / 256, 256, 0, stream>>>(cnt, N);
  count_kernel<<<(E + 255) / 256, 256, 0, stream>>>(dst, cnt, E, N);
  scan_kernel<<<1, 1024, 0, stream>>>(cnt, row_ptr, N);
  dinv_cursor_kernel<<<(N + 255) / 256, 256, 0, stream>>>(cnt, row_ptr, dinv, cursor, N);
  fill_kernel<<<(E + 255) / 256, 256, 0, stream>>>(src, dst, dinv, cursor, edge, E, N);

  const int agg_blocks = (N * 64 + 255) / 256;  // one wave per node

  // ---- layer 1: ax = A_hat x ; hb = bf16(relu(ax @ W1 + b1)) -> d_out ----
  agg128_kernel<<<agg_blocks, 256, 0, stream>>>(x, row_ptr, edge, dinv, buf, N);
  gemm_kernel<128, true, true><<<(N + 31) / 32, 256, 0, stream>>>(buf, W1, b1, hb, N);

  // ---- layer 2: ah = A_hat hb ; out = ah @ W2 + b2 -> d_out (fp32) ----
  agg256_kernel<<<agg_blocks, 256, 0, stream>>>(hb, row_ptr, edge, dinv, buf, N);
  gemm_kernel<256, false, false><<<(N + 31) / 32, 256, 0, stream>>>(buf, W2, b2, d_out, N);
}

// Round 13
// 999.490 us; speedup vs baseline: 1.4592x; 1.1843x over previous
//
#include <hip/hip_runtime.h>

// GCN 2-layer forward on MI355X.
// Pipeline: decode edges -> CSR build -> xconv(bf16) -> agg128(bf16 x) ->
//           MFMA-gemm1(+b1+relu, bf16 out) -> agg256(bf16 h) -> MFMA-gemm2.
// R8/R9/R11 established: agg kernels are fabric-byte-bound (batch depth flat,
//   store policy flat, bytes halved -> time halved). R11: bf16 h gather
//   confirmed (473->226us, FETCH 1.6->0.78GB, absmax 1.95e-3 passing).
// R12: apply byte-theory to agg128 (bf16 x, conversion in dead d_out upper
//   half) + replace VALU fp32 GEMMs with bf16 MFMA (16x16x32, XOR-swizzled
//   LDS A-tile, pre-transposed bf16 W). fp32 accumulate everywhere.

#define DF 256  // GEMM output width (both layers)

typedef float f4v __attribute__((ext_vector_type(4)));
typedef short bf16x8 __attribute__((ext_vector_type(8)));
typedef float f32x4 __attribute__((ext_vector_type(4)));

__device__ inline void nt_store4(float* p, float4 v) {
  f4v t;
  t.x = v.x; t.y = v.y; t.z = v.z; t.w = v.w;
  __builtin_nontemporal_store(t, (f4v*)p);
}
__device__ inline unsigned short f2bf(float f) {  // round-to-nearest-even
  unsigned u = __float_as_uint(f);
  return (unsigned short)((u + 0x7FFFu + ((u >> 16) & 1u)) >> 16);
}
__device__ inline float bf2f(unsigned short h) {
  return __uint_as_float(((unsigned)h) << 16);
}

// ---------------- utility ----------------
__global__ __launch_bounds__(256) void zero_i32(int* __restrict__ p, int n) {
  int i = blockIdx.x * blockDim.x + threadIdx.x;
  if (i < n) p[i] = 0;
}

// ---------------- edge_index dtype detection (int64 vs int32) ----------------
__global__ __launch_bounds__(256) void detect_kernel(const int* __restrict__ ei32,
                                                     int n_logical,
                                                     int* __restrict__ flag) {
  __shared__ int s_nonzero;
  if (threadIdx.x == 0) s_nonzero = 0;
  __syncthreads();
  const int n_half = n_logical >> 1;
  int step = n_half / 1024;
  if (step < 1) step = 1;
  for (int k = threadIdx.x; k < 1024; k += 256) {
    long idx = (long)k * step;
    if (idx < n_half && ei32[2 * idx + 1] != 0) atomicOr(&s_nonzero, 1);
  }
  __syncthreads();
  if (threadIdx.x == 0) flag[0] = s_nonzero ? 0 : 1;  // 1 => int64
}

// ---------------- decode to canonical int32 ----------------
__global__ __launch_bounds__(256) void convert_kernel(const int* __restrict__ ei32,
                                                      const int* __restrict__ flag,
                                                      int* __restrict__ conv, int n) {
  int i = blockIdx.x * blockDim.x + threadIdx.x;
  if (i < n) conv[i] = flag[0] ? ei32[2 * (size_t)i] : ei32[i];
}

// ---------------- x -> bf16 (8 elems/thread) ----------------
__global__ __launch_bounds__(256) void xconv_kernel(const float* __restrict__ x,
                                                    unsigned short* __restrict__ xb,
                                                    int n8) {
  int i = blockIdx.x * blockDim.x + threadIdx.x;
  if (i < n8) {
    const float4 v0 = *(const float4*)&x[(size_t)i * 8];
    const float4 v1 = *(const float4*)&x[(size_t)i * 8 + 4];
    unsigned p0 = f2bf(v0.x) | ((unsigned)f2bf(v0.y) << 16);
    unsigned p1 = f2bf(v0.z) | ((unsigned)f2bf(v0.w) << 16);
    unsigned p2 = f2bf(v1.x) | ((unsigned)f2bf(v1.y) << 16);
    unsigned p3 = f2bf(v1.z) | ((unsigned)f2bf(v1.w) << 16);
    *(uint4*)&xb[(size_t)i * 8] = make_uint4(p0, p1, p2, p3);
  }
}

// ---------------- W[K,256] fp32 -> Wt[256][K] bf16 (transpose+convert) ----------------
__global__ __launch_bounds__(256) void wconv_kernel(const float* __restrict__ W,
                                                    unsigned short* __restrict__ Wt, int K) {
  int idx = blockIdx.x * blockDim.x + threadIdx.x;
  if (idx < K * 256) {
    int k = idx / 256, c = idx % 256;
    Wt[c * K + k] = f2bf(W[idx]);
  }
}

// ---------------- degree histogram ----------------
__global__ __launch_bounds__(256) void count_kernel(const int* __restrict__ dst,
                                                    int* __restrict__ cnt, int E, int n) {
  int i = blockIdx.x * blockDim.x + threadIdx.x;
  if (i < E) {
    int d = dst[i];
    if ((unsigned)d < (unsigned)n) atomicAdd(&cnt[d], 1);
  }
}

// ---------------- single-block exclusive scan over n counts ----------------
__global__ __launch_bounds__(1024) void scan_kernel(const int* __restrict__ cnt,
                                                    int* __restrict__ row_ptr, int n) {
  __shared__ int wsum[16];
  __shared__ int s_base;
  const int tid = threadIdx.x;
  const int lane = tid & 63;
  const int wid = tid >> 6;
  if (tid == 0) s_base = 0;
  __syncthreads();
  for (int start = 0; start < n; start += 4096) {
    const int i0 = start + tid * 4;
    int v[4];
#pragma unroll
    for (int u = 0; u < 4; ++u) v[u] = (i0 + u < n) ? cnt[i0 + u] : 0;
    const int tsum = v[0] + v[1] + v[2] + v[3];
    int sc = tsum;
#pragma unroll
    for (int off = 1; off < 64; off <<= 1) {
      int t = __shfl_up(sc, off);
      if (lane >= off) sc += t;
    }
    if (lane == 63) wsum[wid] = sc;
    __syncthreads();
    if (wid == 0) {
      int ws = (lane < 16) ? wsum[lane] : 0;
#pragma unroll
      for (int off = 1; off < 16; off <<= 1) {
        int t = __shfl_up(ws, off);
        if (lane >= off) ws += t;
      }
      if (lane < 16) wsum[lane] = ws;
    }
    __syncthreads();
    int base = s_base + (wid > 0 ? wsum[wid - 1] : 0) + (sc - tsum);
#pragma unroll
    for (int u = 0; u < 4; ++u) {
      if (i0 + u < n) row_ptr[i0 + u] = base;
      base += v[u];
    }
    __syncthreads();
    if (tid == 1023) s_base += wsum[15];
    __syncthreads();
  }
  if (tid == 0) row_ptr[n] = s_base;
}

// ---------------- dinv = rsqrt(deg+1), cursor = row_ptr copy ----------------
__global__ __launch_bounds__(256) void dinv_cursor_kernel(const int* __restrict__ cnt,
                                                          const int* __restrict__ row_ptr,
                                                          float* __restrict__ dinv,
                                                          int* __restrict__ cursor, int n) {
  int i = blockIdx.x * blockDim.x + threadIdx.x;
  if (i < n) {
    dinv[i] = rsqrtf((float)(cnt[i] + 1));
    cursor[i] = row_ptr[i];
  }
}

// ---------------- CSR fill: edge[] = {src, dinv[src]*dinv[dst]} packed ----------------
__global__ __launch_bounds__(256) void fill_kernel(const int* __restrict__ src,
                                                   const int* __restrict__ dst,
                                                   const float* __restrict__ dinv,
                                                   int* __restrict__ cursor,
                                                   int2* __restrict__ edge, int E, int n) {
  int i = blockIdx.x * blockDim.x + threadIdx.x;
  if (i < E) {
    int s = src[i], d = dst[i];
    if ((unsigned)s < (unsigned)n && (unsigned)d < (unsigned)n) {
      int pos = atomicAdd(&cursor[d], 1);
      edge[pos] = make_int2(s, __float_as_int(dinv[s] * dinv[d]));
    }
  }
}

// ---------------- MFMA bf16 GEMM: out = X[M,K](fp32) @ W(bf16 Wt[256][K]) + b ----------------
// 256 threads = 4 waves; 32-row M-tile (M%32==0), 256 cols; wave w owns cols
// [w*64, w*64+64). A staged fp32->bf16 in XOR-swizzled LDS (G4); B frags read
// from pre-transposed Wt (lane's 8 k-elems contiguous). acc fp32.
// Frag maps (m89-verified): A row=l&15,k=(l>>4)*8+j; B col=l&15 same k;
// D col=l&15,row=(l>>4)*4+r.
template <int K, bool RELU, bool OBF16>
__global__ __launch_bounds__(256) void gemm_kernel(const float* __restrict__ X,
                                                   const unsigned short* __restrict__ Wt,
                                                   const float* __restrict__ bias,
                                                   void* __restrict__ outv, int M) {
  __shared__ unsigned short as_[32 * K];  // 8KB (K=128) / 16KB (K=256)
  const int t = threadIdx.x;
  const int row0 = blockIdx.x * 32;

  // stage A tile: fp32 -> bf16, swizzled write (16B chunks)
  for (int i = t; i < 4 * K; i += 256) {  // 32 rows * K/8 chunks
    int r = i / (K / 8);
    int kk = (i % (K / 8)) * 8;
    int gr = row0 + r;
    float4 v0 = make_float4(0.f, 0.f, 0.f, 0.f), v1 = v0;
    if (gr < M) {
      v0 = *(const float4*)&X[(size_t)gr * K + kk];
      v1 = *(const float4*)&X[(size_t)gr * K + kk + 4];
    }
    unsigned p0 = f2bf(v0.x) | ((unsigned)f2bf(v0.y) << 16);
    unsigned p1 = f2bf(v0.z) | ((unsigned)f2bf(v0.w) << 16);
    unsigned p2 = f2bf(v1.x) | ((unsigned)f2bf(v1.y) << 16);
    unsigned p3 = f2bf(v1.z) | ((unsigned)f2bf(v1.w) << 16);
    unsigned byte = (unsigned)((r * K + kk) * 2) ^ ((unsigned)(r & 7) << 4);
    *(uint4*)((char*)as_ + byte) = make_uint4(p0, p1, p2, p3);
  }
  __syncthreads();

  const int l = t & 63;
  const int wv = t >> 6;           // wave id 0..3 -> col block
  const int lc = l & 15;           // frag col/row lane component
  const int lk = (l >> 4) * 8;     // frag k offset

  f32x4 acc[2][4];
#pragma unroll
  for (int i = 0; i < 2; ++i)
#pragma unroll
    for (int j = 0; j < 4; ++j) acc[i][j] = (f32x4)0.f;

#pragma unroll
  for (int ks = 0; ks < K / 32; ++ks) {
    bf16x8 a[2];
#pragma unroll
    for (int mrep = 0; mrep < 2; ++mrep) {
      int row = mrep * 16 + lc;
      unsigned byte = (unsigned)((row * K + ks * 32 + lk) * 2) ^ ((unsigned)(row & 7) << 4);
      a[mrep] = *(const bf16x8*)((const char*)as_ + byte);
    }
    bf16x8 b[4];
#pragma unroll
    for (int nf = 0; nf < 4; ++nf) {
      int col = wv * 64 + nf * 16 + lc;
      b[nf] = *(const bf16x8*)&Wt[(size_t)col * K + ks * 32 + lk];
    }
#pragma unroll
    for (int mrep = 0; mrep < 2; ++mrep)
#pragma unroll
      for (int nf = 0; nf < 4; ++nf)
        acc[mrep][nf] = __builtin_amdgcn_mfma_f32_16x16x32_bf16(a[mrep], b[nf], acc[mrep][nf], 0, 0, 0);
  }

  // epilogue: D col=lc, row=(l>>4)*4+r
#pragma unroll
  for (int nf = 0; nf < 4; ++nf) {
    int gcol = wv * 64 + nf * 16 + lc;
    float bv = bias[gcol];
#pragma unroll
    for (int mrep = 0; mrep < 2; ++mrep) {
#pragma unroll
      for (int r = 0; r < 4; ++r) {
        int grow = row0 + mrep * 16 + (l >> 4) * 4 + r;
        if (grow < M) {
          float val = acc[mrep][nf][r] + bv;
          if (RELU) val = fmaxf(val, 0.f);
          if (OBF16)
            ((unsigned short*)outv)[(size_t)grow * DF + gcol] = f2bf(val);
          else
            ((float*)outv)[(size_t)grow * DF + gcol] = val;
        }
      }
    }
  }
}

// ---------------- CSR aggregation, D=256, bf16 source: one wave/node, batch-16 ----------------
__global__ __launch_bounds__(256) void agg256_kernel(const unsigned short* __restrict__ hb,
                                                     const int* __restrict__ row_ptr,
                                                     const int2* __restrict__ edge,
                                                     const float* __restrict__ dinv,
                                                     float* __restrict__ out, int n) {
  int wid = (blockIdx.x * blockDim.x + threadIdx.x) >> 6;
  int lane = threadIdx.x & 63;
  if (wid >= n) return;
  int start = row_ptr[wid];
  int end = row_ptr[wid + 1];
  const int foff = lane * 4;

  float4 acc = make_float4(0.f, 0.f, 0.f, 0.f);
  for (int base = start; base < end; base += 64) {
    int e = base + lane;
    int ce = 0;
    float we = 0.f;
    if (e < end) {
      long long ev = __builtin_nontemporal_load((const long long*)edge + e);
      ce = (int)(ev & 0xffffffffLL);
      we = __int_as_float((int)(ev >> 32));
    }
    int m = end - base;
    if (m > 64) m = 64;
    int j = 0;
    for (; j + 16 <= m; j += 16) {
      ushort4 hq[16];
      float ww[16];
#pragma unroll
      for (int u = 0; u < 16; ++u) {
        int s = __shfl(ce, j + u);
        ww[u] = __shfl(we, j + u);
        hq[u] = *(const ushort4*)&hb[(size_t)s * 256 + foff];
      }
#pragma unroll
      for (int u = 0; u < 16; ++u) {
        acc.x = fmaf(bf2f(hq[u].x), ww[u], acc.x);
        acc.y = fmaf(bf2f(hq[u].y), ww[u], acc.y);
        acc.z = fmaf(bf2f(hq[u].z), ww[u], acc.z);
        acc.w = fmaf(bf2f(hq[u].w), ww[u], acc.w);
      }
    }
    for (; j + 8 <= m; j += 8) {
      ushort4 hq[8];
      float ww[8];
#pragma unroll
      for (int u = 0; u < 8; ++u) {
        int s = __shfl(ce, j + u);
        ww[u] = __shfl(we, j + u);
        hq[u] = *(const ushort4*)&hb[(size_t)s * 256 + foff];
      }
#pragma unroll
      for (int u = 0; u < 8; ++u) {
        acc.x = fmaf(bf2f(hq[u].x), ww[u], acc.x);
        acc.y = fmaf(bf2f(hq[u].y), ww[u], acc.y);
        acc.z = fmaf(bf2f(hq[u].z), ww[u], acc.z);
        acc.w = fmaf(bf2f(hq[u].w), ww[u], acc.w);
      }
    }
    for (; j < m; ++j) {
      int s = __shfl(ce, j);
      float ww = __shfl(we, j);
      ushort4 hq = *(const ushort4*)&hb[(size_t)s * 256 + foff];
      acc.x = fmaf(bf2f(hq.x), ww, acc.x);
      acc.y = fmaf(bf2f(hq.y), ww, acc.y);
      acc.z = fmaf(bf2f(hq.z), ww, acc.z);
      acc.w = fmaf(bf2f(hq.w), ww, acc.w);
    }
  }
  float di = dinv[wid];
  float sw = di * di;
  ushort4 hq = *(const ushort4*)&hb[(size_t)wid * 256 + foff];
  acc.x = fmaf(bf2f(hq.x), sw, acc.x);
  acc.y = fmaf(bf2f(hq.y), sw, acc.y);
  acc.z = fmaf(bf2f(hq.z), sw, acc.z);
  acc.w = fmaf(bf2f(hq.w), sw, acc.w);
  nt_store4(&out[(size_t)wid * 256 + foff], acc);
}

// ---------------- CSR aggregation, D=128, bf16 source: half-wave/edge, batch-32 ----------------
// Lane loads ushort4 (8B): 32 lanes x 8B = full 256B bf16 row.
__global__ __launch_bounds__(256) void agg128_kernel(const unsigned short* __restrict__ xb,
                                                     const int* __restrict__ row_ptr,
                                                     const int2* __restrict__ edge,
                                                     const float* __restrict__ dinv,
                                                     float* __restrict__ out, int n) {
  int wid = (blockIdx.x * blockDim.x + threadIdx.x) >> 6;
  int lane = threadIdx.x & 63;
  if (wid >= n) return;
  int start = row_ptr[wid];
  int end = row_ptr[wid + 1];
  const int half = lane >> 5;
  const int foff = (lane & 31) * 4;

  float4 acc = make_float4(0.f, 0.f, 0.f, 0.f);
  for (int base = start; base < end; base += 64) {
    int e = base + lane;
    int ce = 0;
    float we = 0.f;
    if (e < end) {
      long long ev = __builtin_nontemporal_load((const long long*)edge + e);
      ce = (int)(ev & 0xffffffffLL);
      we = __int_as_float((int)(ev >> 32));
    }
    int m = end - base;
    if (m > 64) m = 64;
    int j = 0;
    for (; j + 32 <= m; j += 32) {
      ushort4 hq[16];
      float ww[16];
#pragma unroll
      for (int u = 0; u < 16; ++u) {
        int idx = j + 2 * u + half;
        int s = __shfl(ce, idx);
        ww[u] = __shfl(we, idx);
        hq[u] = *(const ushort4*)&xb[(size_t)s * 128 + foff];
      }
#pragma unroll
      for (int u = 0; u < 16; ++u) {
        acc.x = fmaf(bf2f(hq[u].x), ww[u], acc.x);
        acc.y = fmaf(bf2f(hq[u].y), ww[u], acc.y);
        acc.z = fmaf(bf2f(hq[u].z), ww[u], acc.z);
        acc.w = fmaf(bf2f(hq[u].w), ww[u], acc.w);
      }
    }
    for (; j + 2 <= m; j += 2) {
      int idx = j + half;
      int s = __shfl(ce, idx);
      float ww = __shfl(we, idx);
      ushort4 hq = *(const ushort4*)&xb[(size_t)s * 128 + foff];
      acc.x = fmaf(bf2f(hq.x), ww, acc.x);
      acc.y = fmaf(bf2f(hq.y), ww, acc.y);
      acc.z = fmaf(bf2f(hq.z), ww, acc.z);
      acc.w = fmaf(bf2f(hq.w), ww, acc.w);
    }
    if (j < m) {
      int s = __shfl(ce, j);
      float ww = __shfl(we, j);
      if (half == 0) {
        ushort4 hq = *(const ushort4*)&xb[(size_t)s * 128 + foff];
        acc.x = fmaf(bf2f(hq.x), ww, acc.x);
        acc.y = fmaf(bf2f(hq.y), ww, acc.y);
        acc.z = fmaf(bf2f(hq.z), ww, acc.z);
        acc.w = fmaf(bf2f(hq.w), ww, acc.w);
      }
    }
  }
  acc.x += __shfl_xor(acc.x, 32);
  acc.y += __shfl_xor(acc.y, 32);
  acc.z += __shfl_xor(acc.z, 32);
  acc.w += __shfl_xor(acc.w, 32);
  if (half == 0) {
    float di = dinv[wid];
    float sw = di * di;
    ushort4 hq = *(const ushort4*)&xb[(size_t)wid * 128 + foff];
    acc.x = fmaf(bf2f(hq.x), sw, acc.x);
    acc.y = fmaf(bf2f(hq.y), sw, acc.y);
    acc.z = fmaf(bf2f(hq.z), sw, acc.z);
    acc.w = fmaf(bf2f(hq.w), sw, acc.w);
    nt_store4(&out[(size_t)wid * 128 + foff], acc);
  }
}

// ---------------- launch ----------------
extern "C" void kernel_launch(void* const* d_in, const int* in_sizes, int n_in,
                              void* d_out, int out_size, void* d_ws, size_t ws_size,
                              hipStream_t stream) {
  const float* x = (const float*)d_in[0];
  const int* ei = (const int*)d_in[1];
  const float* W1 = (const float*)d_in[2];
  const float* b1 = (const float*)d_in[3];
  const float* W2 = (const float*)d_in[4];
  const float* b2 = (const float*)d_in[5];

  const int N = in_sizes[0] / 128;   // 100000
  const int NE2 = in_sizes[1];       // 2*E logical int elements
  const int E = NE2 / 2;             // 3200000

  // workspace carve (256B aligned); ~130MB
  char* p = (char*)d_ws;
  auto carve = [&](size_t bytes) {
    void* q = (void*)p;
    p += (bytes + 255) & ~(size_t)255;
    return q;
  };
  int* flag = (int*)carve(4);
  int* cnt = (int*)carve((size_t)N * 4);
  int* row_ptr = (int*)carve((size_t)(N + 1) * 4);
  int* cursor = (int*)carve((size_t)N * 4);
  float* dinv = (float*)carve((size_t)N * 4);
  int2* edge = (int2*)carve((size_t)E * 8);
  unsigned short* Wt1 = (unsigned short*)carve(128 * 256 * 2);  // [256][128]
  unsigned short* Wt2 = (unsigned short*)carve(256 * 256 * 2);  // [256][256]
  float* buf = (float*)carve((size_t)N * DF * 4);  // 102.4MB; ax & ah (fp32)
  // decoded edge_index aliases buf's head (dead before agg128 writes buf)
  int* conv = (int*)buf;
  const int* src = conv;
  const int* dst = conv + E;
  // d_out layout during pipeline: [0,51.2MB) hb bf16; [51.2,76.8MB) xb bf16.
  unsigned short* hb = (unsigned short*)d_out;
  unsigned short* xb = (unsigned short*)((char*)d_out + (size_t)N * 256 * 2);

  // ---- decode edge_index + dtype conversions ----
  detect_kernel<<<1, 256, 0, stream>>>(ei, NE2, flag);
  convert_kernel<<<(NE2 + 255) / 256, 256, 0, stream>>>(ei, flag, conv, NE2);
  xconv_kernel<<<(N * 128 / 8 + 255) / 256, 256, 0, stream>>>(x, xb, N * 128 / 8);
  wconv_kernel<<<(128 * 256 + 255) / 256, 256, 0, stream>>>(W1, Wt1, 128);
  wconv_kernel<<<(256 * 256 + 255) / 256, 256, 0, stream>>>(W2, Wt2, 256);

  // ---- CSR build ----
  zero_i32<<<(N + 255) / 256, 256, 0, stream>>>(cnt, N);
  count_kernel<<<(E + 255) / 256, 256, 0, stream>>>(dst, cnt, E, N);
  scan_kernel<<<1, 1024, 0, stream>>>(cnt, row_ptr, N);
  dinv_cursor_kernel<<<(N + 255) / 256, 256, 0, stream>>>(cnt, row_ptr, dinv, cursor, N);
  fill_kernel<<<(E + 255) / 256, 256, 0, stream>>>(src, dst, dinv, cursor, edge, E, N);

  const int agg_blocks = (N * 64 + 255) / 256;

  // ---- layer 1: ax = A_hat x (bf16 gather) ; hb = bf16(relu(ax@W1+b1)) ----
  agg128_kernel<<<agg_blocks, 256, 0, stream>>>(xb, row_ptr, edge, dinv, buf, N);
  gemm_kernel<128, true, true><<<(N + 31) / 32, 256, 0, stream>>>(buf, Wt1, b1, hb, N);

  // ---- layer 2: ah = A_hat hb ; out = ah@W2+b2 (fp32) ----
  agg256_kernel<<<agg_blocks, 256, 0, stream>>>(hb, row_ptr, edge, dinv, buf, N);
  gemm_kernel<256, false, false><<<(N + 31) / 32, 256, 0, stream>>>(buf, Wt2, b2, d_out, N);
}